// Round 4
// baseline (733.664 us; speedup 1.0000x reference)
//
#include <hip/hip_runtime.h>
#include <stdint.h>

// BiRealConv2d: y = conv2d(sign(x), scale[o]*sign(w)), NCHW, 3x3, pad 1.
// Exact integer XNOR-popcount formulation.
// R4: conv computes a 4-tall pixel column per thread (taps = 6x3 uint4 in
//     VGPRs; 9 ds_read_b128 of weights per o-iter serve 4 outputs -> weight
//     pipe /4), all arithmetic in u32 (kills i64 popcount-add chains), and
//     border correction folded in via per-lane LDS table f2p[o][pat]
//     (fix_border kernel deleted).

#define HH 112
#define WW 112
#define CC 128
#define OO 128
#define NN 32
#define HP 114   // padded
#define WP 114

// ---------------- pass 1: pack sign(x); also zeroes the halo ----------------------
__global__ __launch_bounds__(256) void pack_x_kernel(const float* __restrict__ x,
                                                     uint32_t* __restrict__ xb32) {
  int t = threadIdx.x;
  int lane = t & 63;
  int grp = t >> 6;                   // channels [grp*32, grp*32+32)
  int wseg = blockIdx.x * 64 + lane;  // 0..127
  int hp = blockIdx.y;                // padded row 0..113
  int n = blockIdx.z;
  size_t rowbase = ((size_t)n * HP + hp) * WP;
  if (hp == 0 || hp == HP - 1) {      // top/bottom halo rows
    if (wseg < WP) xb32[(rowbase + wseg) * 4 + grp] = 0u;
    return;
  }
  int h = hp - 1;
  if (wseg < WW) {
    const float* xp = x + (((size_t)n * CC + grp * 32) * HH + h) * WW + wseg;
    uint32_t mm = 0u;
#pragma unroll
    for (int b = 0; b < 32; b++) {
      float v = xp[(size_t)b * (HH * WW)];
      mm |= (v > 0.0f) ? (1u << b) : 0u;   // bit=1 -> +1, bit=0 -> -1
    }
    xb32[(rowbase + (wseg + 1)) * 4 + grp] = mm;
  } else if (wseg == WW) {
    xb32[(rowbase + (WP - 1)) * 4 + grp] = 0u;   // right halo
  } else if (wseg == WW + 1) {
    xb32[(rowbase + 0) * 4 + grp] = 0u;          // left halo
  }
}

// ---------------- pass 0: weight bitmasks + fused epilogue tables -----------------
// s2[o] = 2*scale;  f2p[o*9+pat] = scale * c2[pat]  (out = f2p - s2*pc)
__global__ __launch_bounds__(256) void prep_w_kernel(const float* __restrict__ wt,
                                                     uint64_t* __restrict__ wbits,
                                                     float* __restrict__ s2,
                                                     float* __restrict__ f2p) {
  int o = blockIdx.x;
  const float* wo = wt + (size_t)o * (CC * 9);
  __shared__ unsigned int bits[9][4];
  __shared__ float red[256];
  int t = threadIdx.x;
  if (t < 36) ((unsigned int*)bits)[t] = 0u;
  __syncthreads();
  float s = 0.0f;
  for (int idx = t; idx < CC * 9; idx += 256) {
    float v = wo[idx];
    s += fabsf(v);
    int ci = idx / 9, tap = idx % 9;      // OIHW: tap = kh*3+kw
    if (v > 0.0f) atomicOr(&bits[tap][ci >> 5], 1u << (ci & 31));
  }
  red[t] = s;
  __syncthreads();
  for (int st = 128; st > 0; st >>= 1) {
    if (t < st) red[t] += red[t + st];
    __syncthreads();
  }
  if (t == 0) {
    float sc = red[0] * (1.0f / 1152.0f);
    int c[9];
#pragma unroll
    for (int tap = 0; tap < 9; tap++) {
      uint64_t lo = (uint64_t)bits[tap][0] | ((uint64_t)bits[tap][1] << 32);
      uint64_t hi = (uint64_t)bits[tap][2] | ((uint64_t)bits[tap][3] << 32);
      wbits[o * 18 + tap * 2]     = lo;   // memory = u32 words [b0,b1,b2,b3]
      wbits[o * 18 + tap * 2 + 1] = hi;
      c[tap] = 128 - 2 * (__builtin_popcountll(lo) + __builtin_popcountll(hi));
    }
    for (int ph = 0; ph < 3; ph++)
      for (int pw = 0; pw < 3; pw++) {
        int sum = 0;
        for (int tap = 0; tap < 9; tap++) {
          int kh = tap / 3, kw = tap % 3;
          bool inv = (ph == 0 && kh == 0) || (ph == 2 && kh == 2) ||
                     (pw == 0 && kw == 0) || (pw == 2 && kw == 2);
          if (inv) sum += c[tap];          // spurious halo term
        }
        f2p[o * 9 + ph * 3 + pw] = sc * (float)(1152 - sum);
      }
    s2[o] = 2.0f * sc;
  }
}

// ---------------- pass 2: XNOR-popcount conv, 4-pixel column per thread -----------
__global__ __launch_bounds__(256, 3) void conv_kernel(const uint32_t* __restrict__ xb,
                                                      const uint64_t* __restrict__ wbits,
                                                      const float* __restrict__ s2,
                                                      const float* __restrict__ f2p,
                                                      float* __restrict__ out) {
  __shared__ uint4 lwq[OO * 9];     // 18,432 B: weights, [o*9 + tap]
  __shared__ float lfix[OO * 9];    //  4,608 B: f2p table
  int t = threadIdx.x;
  {
    const uint4* wq = (const uint4*)wbits;
    for (int i = t; i < OO * 9; i += 256) lwq[i] = wq[i];
    for (int i = t; i < OO * 9; i += 256) lfix[i] = f2p[i];
  }
  int og = __builtin_amdgcn_readfirstlane(t >> 6);  // wave-uniform o-group
  int wl = t & 63;
  int w = blockIdx.x * 64 + wl;
  int h0 = blockIdx.y * 4;          // rows h0..h0+3
  int n = blockIdx.z;
  bool valid = (w < WW);
  __syncthreads();
  if (!valid) return;

  int pw = (w == 0) ? 0 : ((w == WW - 1) ? 2 : 1);
  int patb[4];                      // pat*4 bytes per pixel row
#pragma unroll
  for (int r = 0; r < 4; r++) {
    int hh = h0 + r;
    int ph = (hh == 0) ? 0 : ((hh == HH - 1) ? 2 : 1);
    patb[r] = (ph * 3 + pw) * 4;
  }

  // taps: 6 rows (h0-1 .. h0+4 in padded coords h0..h0+5) x 3 cols, uint4 each.
  const uint4* xbase = (const uint4*)xb + (((size_t)n * HP + h0) * WP + w);
  uint4 xq[18];
#pragma unroll
  for (int rr = 0; rr < 6; rr++)
#pragma unroll
    for (int cc = 0; cc < 3; cc++)
      xq[rr * 3 + cc] = xbase[(size_t)rr * WP + cc];
#pragma unroll
  for (int i = 0; i < 18; i++)
    asm volatile("" : "+v"(xq[i].x), "+v"(xq[i].y), "+v"(xq[i].z), "+v"(xq[i].w));

  size_t obase = (((size_t)(n * OO + og * 32)) * HH + h0) * WW + w;
  float* op = out + obase;
#pragma unroll 1
  for (int j = 0; j < 32; j++) {
    int o = (og << 5) + j;                       // wave-uniform -> s_load s2
    const uint4* wq = lwq + o * 9;               // LDS broadcast, imm offsets
    int pc0 = 0, pc1 = 0, pc2 = 0, pc3 = 0;
#pragma unroll
    for (int kh = 0; kh < 3; kh++)
#pragma unroll
      for (int kw = 0; kw < 3; kw++) {
        uint4 wv = wq[kh * 3 + kw];
        uint4 a0 = xq[(0 + kh) * 3 + kw];
        pc0 += __builtin_popcount(a0.x ^ wv.x); pc0 += __builtin_popcount(a0.y ^ wv.y);
        pc0 += __builtin_popcount(a0.z ^ wv.z); pc0 += __builtin_popcount(a0.w ^ wv.w);
        uint4 a1 = xq[(1 + kh) * 3 + kw];
        pc1 += __builtin_popcount(a1.x ^ wv.x); pc1 += __builtin_popcount(a1.y ^ wv.y);
        pc1 += __builtin_popcount(a1.z ^ wv.z); pc1 += __builtin_popcount(a1.w ^ wv.w);
        uint4 a2 = xq[(2 + kh) * 3 + kw];
        pc2 += __builtin_popcount(a2.x ^ wv.x); pc2 += __builtin_popcount(a2.y ^ wv.y);
        pc2 += __builtin_popcount(a2.z ^ wv.z); pc2 += __builtin_popcount(a2.w ^ wv.w);
        uint4 a3 = xq[(3 + kh) * 3 + kw];
        pc3 += __builtin_popcount(a3.x ^ wv.x); pc3 += __builtin_popcount(a3.y ^ wv.y);
        pc3 += __builtin_popcount(a3.z ^ wv.z); pc3 += __builtin_popcount(a3.w ^ wv.w);
      }
    const float* fx = (const float*)((const char*)(lfix + o * 9));
    float sj = s2[o];
    op[0 * WW] = *(const float*)((const char*)fx + patb[0]) - sj * (float)pc0;
    op[1 * WW] = *(const float*)((const char*)fx + patb[1]) - sj * (float)pc1;
    op[2 * WW] = *(const float*)((const char*)fx + patb[2]) - sj * (float)pc2;
    op[3 * WW] = *(const float*)((const char*)fx + patb[3]) - sj * (float)pc3;
    op += (size_t)HH * WW;
  }
}

extern "C" void kernel_launch(void* const* d_in, const int* in_sizes, int n_in,
                              void* d_out, int out_size, void* d_ws, size_t ws_size,
                              hipStream_t stream) {
  const float* x  = (const float*)d_in[0];
  const float* wt = (const float*)d_in[1];
  float* out = (float*)d_out;

  char* ws = (char*)d_ws;
  size_t xb_elems = (size_t)NN * HP * WP * 2;       // u64 (6.65 MB), 16B-aligned
  uint64_t* xb    = (uint64_t*)ws;
  size_t off = xb_elems * 8;
  uint64_t* wbits = (uint64_t*)(ws + off); off += (size_t)OO * 18 * 8;
  float* s2       = (float*)(ws + off);    off += (size_t)OO * 4;
  float* f2p      = (float*)(ws + off);    off += (size_t)OO * 9 * 4;

  hipLaunchKernelGGL(pack_x_kernel, dim3(2, HP, NN), dim3(256), 0, stream,
                     x, (uint32_t*)xb);
  hipLaunchKernelGGL(prep_w_kernel, dim3(OO), dim3(256), 0, stream,
                     wt, wbits, s2, f2p);
  hipLaunchKernelGGL(conv_kernel, dim3(2, 28, NN), dim3(256), 0, stream,
                     (const uint32_t*)xb, wbits, s2, f2p, out);
}